// Round 12
// baseline (247.270 us; speedup 1.0000x reference)
//
#include <hip/hip_runtime.h>
#include <hip/hip_bf16.h>

#define N_NODES 50000
#define N_EDGES 800000
#define D 128
#define NEG_SLOPE 0.2f
#define APAD 136                             // LDS row pitch (ushort): 2-way-only bank aliasing

#define FB 196                               // fine buckets: src >> 8 (256 nodes each)
#define BCAP 8192                            // per-bucket region capacity (avg fill ~4096)
#define CHUNK 2048
#define BIN_NBLK ((N_EDGES + CHUNK - 1) / CHUNK)   // 391
#define GROWS 64
#define GGRID ((N_NODES + GROWS - 1) / GROWS)      // 782
#define GEMM_LDS (D * APAD * 2 + GROWS * APAD * 2) // 52224 B

#define SPMM_NODES 16                               // nodes (waves) per fused spmm block
#define SPMM_GRID (N_NODES / SPMM_NODES)            // 3125 exact
#define DL_PITCH 68                                 // per-wave dst-list pitch (ints)
#define SPMM_LDS ((D * APAD + SPMM_NODES * APAD) * 2 + SPMM_NODES * DL_PITCH * 4) // 43520 B

typedef __attribute__((ext_vector_type(8))) short bf16x8;
typedef __attribute__((ext_vector_type(4))) float f32x4;

__device__ inline unsigned short f2bf(float f) {
    union { float f; unsigned u; } v; v.f = f;
    const unsigned r = v.u + 0x7FFF + ((v.u >> 16) & 1);   // round-nearest-even
    return (unsigned short)(r >> 16);
}
__device__ inline unsigned fbits(float f) { union { float f; unsigned u; } v; v.f = f; return v.u; }
__device__ inline float ffrom(unsigned u) { union { unsigned u; float f; } v; v.u = u; return v.f; }

__device__ inline void unpack8(const float4 raw, float* o) {
    const unsigned w0 = fbits(raw.x), w1 = fbits(raw.y), w2 = fbits(raw.z), w3 = fbits(raw.w);
    o[0] = ffrom(w0 << 16); o[1] = ffrom(w0 & 0xffff0000u);
    o[2] = ffrom(w1 << 16); o[3] = ffrom(w1 & 0xffff0000u);
    o[4] = ffrom(w2 << 16); o[5] = ffrom(w2 & 0xffff0000u);
    o[6] = ffrom(w3 << 16); o[7] = ffrom(w3 & 0xffff0000u);
}

// 16-lane (quarter-wave) sum via DPP rotate-adds: pure VALU, no LDS pipe.
// Safe under inter-quarter divergence: each 16-lane row is branch-uniform and
// DPP row ops never read across rows.
__device__ __forceinline__ float rsum16(float t) {
    union { float f; int i; } u, s;
    u.f = t;
    s.i = __builtin_amdgcn_update_dpp(0, u.i, 0x128, 0xF, 0xF, true); u.f += s.f; // ror 8
    s.i = __builtin_amdgcn_update_dpp(0, u.i, 0x124, 0xF, 0xF, true); u.f += s.f; // ror 4
    s.i = __builtin_amdgcn_update_dpp(0, u.i, 0x4E,  0xF, 0xF, true); u.f += s.f; // quad rot 2
    s.i = __builtin_amdgcn_update_dpp(0, u.i, 0x39,  0xF, 0xF, true); u.f += s.f; // quad rot 1
    return u.f;
}

// inclusive scan of 256 values (4 waves) — shfl_up intra-wave, one barrier.
__device__ __forceinline__ int scan256_incl_fast(int* wsum, int t, int v) {
    const int lane = t & 63;
    int x = v;
#pragma unroll
    for (int off = 1; off < 64; off <<= 1) {
        const int u = __shfl_up(x, off, 64);
        if (lane >= off) x += u;
    }
    if (lane == 63) wsum[t >> 6] = x;
    __syncthreads();
    int base = 0;
#pragma unroll
    for (int wv = 0; wv < 3; ++wv)
        base += (wv < (t >> 6)) ? wsum[wv] : 0;
    return x + base;
}

// inclusive scan across a 512-thread block (8 waves); threads t>=256 pass v=0.
__device__ __forceinline__ int scan_incl_512(int* wsum, int t, int v) {
    const int lane = t & 63;
    int x = v;
#pragma unroll
    for (int off = 1; off < 64; off <<= 1) {
        const int u = __shfl_up(x, off, 64);
        if (lane >= off) x += u;
    }
    if (lane == 63) wsum[t >> 6] = x;
    __syncthreads();
    int base = 0;
#pragma unroll
    for (int wv = 0; wv < 7; ++wv)
        base += (wv < (t >> 6)) ? wsum[wv] : 0;
    return x + base;
}

// stage a 128x128 bf16 matrix (transposed layout [n][k]) into LDS [n][APAD]
__device__ __forceinline__ void stage_B_lds(unsigned short* Bs, const ushort* __restrict__ BT) {
    const int tid = threadIdx.x;
#pragma unroll
    for (int i = 0; i < 8; ++i) {
        const int idx = tid + i * 256;
        const int row = idx >> 4;
        const int c8 = (idx & 15) << 3;
        const float4 v = ((const float4*)BT)[idx];
        *(float4*)&Bs[row * APAD + c8] = v;
    }
}

// MFMA: C[rb..rb+63][0..127] = As(LDS) @ Bs(LDS, transposed), fp32 acc
template <bool OUT_F32>
__device__ __forceinline__ void mfma_from_lds(const unsigned short* Bs,
                                              const unsigned short* As,
                                              int rb, float* __restrict__ Cf,
                                              ushort* __restrict__ Cb, int nrows) {
    const int tid = threadIdx.x;
    const int w = tid >> 6, lane = tid & 63, m = lane & 15, kq = lane >> 4;
    f32x4 acc[8] = {};
    const unsigned short* Arow = &As[(w * 16 + m) * APAD + kq * 8];
#pragma unroll
    for (int kc = 0; kc < 4; ++kc) {
        const bf16x8 af = *(const bf16x8*)(Arow + kc * 32);
#pragma unroll
        for (int t2 = 0; t2 < 8; ++t2) {
            const bf16x8 bf = *(const bf16x8*)&Bs[(t2 * 16 + m) * APAD + kc * 32 + kq * 8];
            acc[t2] = __builtin_amdgcn_mfma_f32_16x16x32_bf16(af, bf, acc[t2], 0, 0, 0);
        }
    }
    const int orow0 = rb + w * 16 + kq * 4;   // C/D: col=lane&15, row=(lane>>4)*4+reg [m89]
#pragma unroll
    for (int t2 = 0; t2 < 8; ++t2) {
#pragma unroll
        for (int r = 0; r < 4; ++r) {
            const int row = orow0 + r;
            if (row < nrows) {
                const size_t o = (size_t)row * D + t2 * 16 + m;
                if (OUT_F32) Cf[o] = acc[t2][r];
                else         Cb[o] = f2bf(acc[t2][r]);
            }
        }
    }
}

// ---- K0 (tiny): weight prep + zero bucket_fill. MUST be its own dispatch:
// consumers (K1 gemm1 branch / spmm_fused) are separate launches -> stream-ordered.
__global__ __launch_bounds__(256) void prep_kernel(const float* __restrict__ W_l,
                                                   const float* __restrict__ W_r,
                                                   const float* __restrict__ W,
                                                   ushort* __restrict__ MbT,
                                                   ushort* __restrict__ WbT,
                                                   int* __restrict__ bucket_fill) {
    if (blockIdx.x == 0) bucket_fill[threadIdx.x] = 0;   // 256 entries
    // MbT[n][k] = (W_l @ W_r^T)[k][n]; WbT[n][k] = W[k][n]
    const int a = blockIdx.x * 2 + (threadIdx.x >> 7);   // k
    const int b2 = threadIdx.x & 127;                    // n
    float acc = 0.f;
#pragma unroll
    for (int c = 0; c < D; c += 4) {
        const float4 wl = *(const float4*)(W_l + a * D + c);
        const float4 wr = *(const float4*)(W_r + b2 * D + c);
        acc += wl.x * wr.x + wl.y * wr.y + wl.z * wr.z + wl.w * wr.w;
    }
    MbT[b2 * D + a] = f2bf(acc);
    WbT[b2 * D + a] = f2bf(W[a * D + b2]);
}

// ---- K1: bin (blocks 0..390) + convert_gemm1 (391..) — binned entries
// packed to ONE int ((src<<16)|dst; both < 2^16). LDS-staged binning kept
// (R14 lesson: per-edge global atomics ~60-75ns each -> 50-60us kernels).
__global__ __launch_bounds__(256) void k1_kernel(const int* __restrict__ src,
                                                 const int* __restrict__ dst,
                                                 int* __restrict__ bucket_fill,
                                                 int* __restrict__ binned,
                                                 const ushort* __restrict__ MbT,
                                                 const float4* __restrict__ Xf4,
                                                 ushort* __restrict__ Xb,
                                                 ushort* __restrict__ hMb) {
    __shared__ __align__(16) char smem[GEMM_LDS];
    const int bx = blockIdx.x;
    const int t = threadIdx.x;

    if (bx < BIN_NBLK) {
        int*  hist     = (int*)smem;                 // 256
        int*  bstart   = hist + 256;                 // 256 (first 4 double as wave-sum scratch)
        int*  reserveS = bstart + 256;               // 256
        int*  fillL    = reserveS + 256;             // 256
        int*  pairs    = fillL + 256;                // CHUNK (8 KB, packed)
        int*  targ     = pairs + CHUNK;              // CHUNK (8 KB)
        const int e0 = bx * CHUNK;

        hist[t] = 0;
        __syncthreads();

        int s[8], d[8], b[8];
#pragma unroll
        for (int i = 0; i < 8; ++i) {
            const int e = e0 + i * 256 + t;
            if (e < N_EDGES) {
                s[i] = src[e]; d[i] = dst[e]; b[i] = s[i] >> 8;
                atomicAdd(&hist[b[i]], 1);
            } else b[i] = -1;
        }
        __syncthreads();
        const int hv = hist[t];
        const int incl = scan256_incl_fast(bstart, t, hv);   // 1 barrier
        const int mystart = incl - hv;
        reserveS[t] = hv ? atomicAdd(&bucket_fill[t], hv) : 0;
        __syncthreads();                 // also fences wave-sum reads before overwrite
        bstart[t] = mystart;
        fillL[t] = mystart;
        __syncthreads();
#pragma unroll
        for (int i = 0; i < 8; ++i) {
            if (b[i] >= 0) {
                const int p = atomicAdd(&fillL[b[i]], 1);
                pairs[p] = (s[i] << 16) | d[i];
                const int pos = reserveS[b[i]] + (p - bstart[b[i]]);
                targ[p] = (pos < BCAP) ? (b[i] * BCAP + pos) : -1;   // overflow guard
            }
        }
        __syncthreads();
        const int nval = min(CHUNK, N_EDGES - e0);
        for (int j = t; j < nval; j += 256)
            if (targ[j] >= 0) binned[targ[j]] = pairs[j];
    } else {
        // ---- convert 64 X-rows fp32->bf16 (global + LDS) then hM = Xb@M ----
        unsigned short* Bs = (unsigned short*)smem;     // [128][APAD]
        unsigned short* As = Bs + D * APAD;             // [64][APAD]
        const int rb = (bx - BIN_NBLK) * GROWS;

        stage_B_lds(Bs, MbT);                           // MbT from K0 (stream-ordered)
#pragma unroll
        for (int i = 0; i < 4; ++i) {
            const int f2 = t + i * 256;
            const int row = f2 >> 4;
            const int c8 = (f2 & 15) << 3;
            ushort4 lo = {0, 0, 0, 0}, hi = {0, 0, 0, 0};
            if (rb + row < N_NODES) {
                const float4 a = Xf4[(size_t)(rb + row) * 32 + (c8 >> 2)];
                const float4 b = Xf4[(size_t)(rb + row) * 32 + (c8 >> 2) + 1];
                lo.x = f2bf(a.x); lo.y = f2bf(a.y); lo.z = f2bf(a.z); lo.w = f2bf(a.w);
                hi.x = f2bf(b.x); hi.y = f2bf(b.y); hi.z = f2bf(b.z); hi.w = f2bf(b.w);
                ushort* gp = Xb + (size_t)(rb + row) * D + c8;
                *(ushort4*)gp = lo;
                *(ushort4*)(gp + 4) = hi;
            }
            *(ushort4*)&As[row * APAD + c8] = lo;
            *(ushort4*)&As[row * APAD + c8 + 4] = hi;
        }
        __syncthreads();
        mfma_from_lds<false>(Bs, As, rb, nullptr, hMb, N_NODES);
    }
}

// ---- K2: fine scatter, one 512-thread block per bucket; builds offsets+sorted_dst ----
__global__ __launch_bounds__(512) void fine_kernel(const int* __restrict__ binned,
                                                   const int* __restrict__ bucket_fill,
                                                   int* __restrict__ offsets,
                                                   int* __restrict__ sorted_dst) {
    __shared__ int cntS[256];
    __shared__ int nh[256];
    __shared__ int fill[256];
    __shared__ int wsum[8];
    __shared__ int dstbuf[BCAP];
    const int b = blockIdx.x;
    const int t = threadIdx.x;

    int cv = 0;
    if (t < 256) cv = (t < FB) ? bucket_fill[t] : 0;
    const int incl = scan_incl_512(wsum, t, cv);        // 1 barrier
    if (t < 256) cntS[t] = incl;
    __syncthreads();
    const int base = (b == 0) ? 0 : cntS[b - 1];
    int cnt = cntS[b] - base;
    if (cnt > BCAP) cnt = BCAP;

    if (t < 256) nh[t] = 0;
    __syncthreads();
    const int* bb = binned + (size_t)b * BCAP;
    for (int e = t; e < cnt; e += 512) atomicAdd(&nh[((unsigned)bb[e] >> 16) & 255], 1);
    __syncthreads();
    const int v = (t < 256) ? nh[t] : 0;
    const int incl2 = scan_incl_512(wsum, t, v);        // 1 barrier
    if (t < 256) {
        const int mystart = incl2 - v;
        const int node = b * 256 + t;
        if (node < N_NODES) offsets[node] = base + mystart;   // exclusive CSR starts
        fill[t] = mystart;
    }
    __syncthreads();
    for (int e = t; e < cnt; e += 512) {
        const int sd = bb[e];
        const int p = atomicAdd(&fill[((unsigned)sd >> 16) & 255], 1);
        dstbuf[p] = sd & 0xFFFF;
    }
    __syncthreads();
    for (int j = t; j < cnt; j += 512)
        sorted_dst[base + j] = dstbuf[j];
}

// ---- K3 (R20): fused SDDMM + SpMM + @W. R11 loop shape (verified local
// optimum: R3/R6/R7/R19 all lost), ONE change: the node's dst-list is
// prefetched ONCE (coalesced, one load/wave) into LDS; the in-loop idx
// loads become uniform LDS broadcast reads -> serial chain per round is
// lds_read(~120cy) + gather instead of global(~300-900cy) + gather.
// deg>64 (P<1e-18 at Poisson(16)) falls back to the original global loop.
// W staged in LDS (R12: gather streaming evicts W from L2).
__global__ __launch_bounds__(1024, 8) void spmm_fused_kernel(const ushort* __restrict__ hMb,
                                                             const ushort* __restrict__ Xb,
                                                             const int* __restrict__ offsets,
                                                             const int* __restrict__ sorted_dst,
                                                             const ushort* __restrict__ WbT,
                                                             float* __restrict__ agg) {
    __shared__ __align__(16) char smem[SPMM_LDS];
    unsigned short* Ws = (unsigned short*)smem;          // [128][APAD] : W (transposed [n][k])
    unsigned short* As = Ws + D * APAD;                  // [16][APAD]  : node rows (bf16)
    int* dstL = (int*)(As + SPMM_NODES * APAD);          // [16][DL_PITCH] : per-wave dst lists
    const int tid = threadIdx.x;

    // stage W: 2048 float4 over 1024 threads
#pragma unroll
    for (int i = 0; i < 2; ++i) {
        const int idx = tid + i * 1024;
        const int row = idx >> 4;
        const int c8 = (idx & 15) << 3;
        const float4 v = ((const float4*)WbT)[idx];
        *(float4*)&Ws[row * APAD + c8] = v;
    }

    const int wave = tid >> 6;
    const int lane = tid & 63;
    const int node = blockIdx.x * SPMM_NODES + wave;     // 3125*16 = 50000 exact
    const int q = lane >> 4;
    const int ql = lane & 15;

    float hm[8];
    unpack8(*(const float4*)(hMb + (size_t)node * D + ql * 8), hm);

    const int start = offsets[node];
    const int end = (node == N_NODES - 1) ? N_EDGES : offsets[node + 1];
    const int deg = end - start;
    const int mydeg = deg < 64 ? deg : 64;

    // one coalesced load per wave: park the dst list in LDS (same-wave
    // producer/consumer; LDS ops are in-order per wave, no barrier needed)
    int* myDst = dstL + wave * DL_PITCH;
    if (lane < mydeg) myDst[lane] = sorted_dst[start + lane];

    float acc[8] = {0.f, 0.f, 0.f, 0.f, 0.f, 0.f, 0.f, 0.f};

    int il = q;                                          // local edge index
    while (il + 12 < mydeg) {
        const int d0 = myDst[il];
        const int d1 = myDst[il + 4];
        const int d2 = myDst[il + 8];
        const int d3 = myDst[il + 12];
        const float4 r0 = *(const float4*)(Xb + (size_t)d0 * D + ql * 8);
        const float4 r1 = *(const float4*)(Xb + (size_t)d1 * D + ql * 8);
        const float4 r2 = *(const float4*)(Xb + (size_t)d2 * D + ql * 8);
        const float4 r3 = *(const float4*)(Xb + (size_t)d3 * D + ql * 8);
        float t0 = 0.f, t1 = 0.f, t2 = 0.f, t3 = 0.f;
        {
            float x[8];
            unpack8(r0, x);
#pragma unroll
            for (int j = 0; j < 8; ++j) t0 = fmaf(hm[j], x[j], t0);
            unpack8(r1, x);
#pragma unroll
            for (int j = 0; j < 8; ++j) t1 = fmaf(hm[j], x[j], t1);
            unpack8(r2, x);
#pragma unroll
            for (int j = 0; j < 8; ++j) t2 = fmaf(hm[j], x[j], t2);
            unpack8(r3, x);
#pragma unroll
            for (int j = 0; j < 8; ++j) t3 = fmaf(hm[j], x[j], t3);
        }
        t0 = rsum16(t0);
        t1 = rsum16(t1);
        t2 = rsum16(t2);
        t3 = rsum16(t3);
        const float e0 = t0 > 0.f ? t0 : NEG_SLOPE * t0;
        const float e1 = t1 > 0.f ? t1 : NEG_SLOPE * t1;
        const float e2 = t2 > 0.f ? t2 : NEG_SLOPE * t2;
        const float e3 = t3 > 0.f ? t3 : NEG_SLOPE * t3;
        {
            float x[8];
            unpack8(r0, x);
#pragma unroll
            for (int j = 0; j < 8; ++j) acc[j] = fmaf(e0, x[j], acc[j]);
            unpack8(r1, x);
#pragma unroll
            for (int j = 0; j < 8; ++j) acc[j] = fmaf(e1, x[j], acc[j]);
            unpack8(r2, x);
#pragma unroll
            for (int j = 0; j < 8; ++j) acc[j] = fmaf(e2, x[j], acc[j]);
            unpack8(r3, x);
#pragma unroll
            for (int j = 0; j < 8; ++j) acc[j] = fmaf(e3, x[j], acc[j]);
        }
        il += 16;
    }
    // masked-parallel tail within the LDS-resident first 64 edges
    if (il < mydeg) {
        const int i1 = il + 4, i2 = il + 8;
        const bool v1 = i1 < mydeg, v2 = i2 < mydeg;
        const int d0 = myDst[il];
        const int d1 = myDst[v1 ? i1 : il];
        const int d2 = myDst[v2 ? i2 : il];
        const float4 r0 = *(const float4*)(Xb + (size_t)d0 * D + ql * 8);
        const float4 r1 = *(const float4*)(Xb + (size_t)d1 * D + ql * 8);
        const float4 r2 = *(const float4*)(Xb + (size_t)d2 * D + ql * 8);
        float t0 = 0.f, t1 = 0.f, t2 = 0.f;
        {
            float x[8];
            unpack8(r0, x);
#pragma unroll
            for (int j = 0; j < 8; ++j) t0 = fmaf(hm[j], x[j], t0);
            unpack8(r1, x);
#pragma unroll
            for (int j = 0; j < 8; ++j) t1 = fmaf(hm[j], x[j], t1);
            unpack8(r2, x);
#pragma unroll
            for (int j = 0; j < 8; ++j) t2 = fmaf(hm[j], x[j], t2);
        }
        t0 = rsum16(t0);
        t1 = rsum16(t1);
        t2 = rsum16(t2);
        float e0 = t0 > 0.f ? t0 : NEG_SLOPE * t0;
        float e1 = t1 > 0.f ? t1 : NEG_SLOPE * t1;
        float e2 = t2 > 0.f ? t2 : NEG_SLOPE * t2;
        e1 = v1 ? e1 : 0.f;
        e2 = v2 ? e2 : 0.f;
        {
            float x[8];
            unpack8(r0, x);
#pragma unroll
            for (int j = 0; j < 8; ++j) acc[j] = fmaf(e0, x[j], acc[j]);
            unpack8(r1, x);
#pragma unroll
            for (int j = 0; j < 8; ++j) acc[j] = fmaf(e1, x[j], acc[j]);
            unpack8(r2, x);
#pragma unroll
            for (int j = 0; j < 8; ++j) acc[j] = fmaf(e2, x[j], acc[j]);
        }
    }
    // deg > 64 overflow (astronomically rare; correctness only): original
    // global-load loop for edges [start+64, end), same quarter-stride order.
    if (deg > 64) {
        int idx = start + 64 + q;
        while (idx + 12 < end) {
            const int d0 = sorted_dst[idx];
            const int d1 = sorted_dst[idx + 4];
            const int d2 = sorted_dst[idx + 8];
            const int d3 = sorted_dst[idx + 12];
            const float4 r0 = *(const float4*)(Xb + (size_t)d0 * D + ql * 8);
            const float4 r1 = *(const float4*)(Xb + (size_t)d1 * D + ql * 8);
            const float4 r2 = *(const float4*)(Xb + (size_t)d2 * D + ql * 8);
            const float4 r3 = *(const float4*)(Xb + (size_t)d3 * D + ql * 8);
            float t0 = 0.f, t1 = 0.f, t2 = 0.f, t3 = 0.f;
            {
                float x[8];
                unpack8(r0, x);
#pragma unroll
                for (int j = 0; j < 8; ++j) t0 = fmaf(hm[j], x[j], t0);
                unpack8(r1, x);
#pragma unroll
                for (int j = 0; j < 8; ++j) t1 = fmaf(hm[j], x[j], t1);
                unpack8(r2, x);
#pragma unroll
                for (int j = 0; j < 8; ++j) t2 = fmaf(hm[j], x[j], t2);
                unpack8(r3, x);
#pragma unroll
                for (int j = 0; j < 8; ++j) t3 = fmaf(hm[j], x[j], t3);
            }
            t0 = rsum16(t0);
            t1 = rsum16(t1);
            t2 = rsum16(t2);
            t3 = rsum16(t3);
            const float e0 = t0 > 0.f ? t0 : NEG_SLOPE * t0;
            const float e1 = t1 > 0.f ? t1 : NEG_SLOPE * t1;
            const float e2 = t2 > 0.f ? t2 : NEG_SLOPE * t2;
            const float e3 = t3 > 0.f ? t3 : NEG_SLOPE * t3;
            {
                float x[8];
                unpack8(r0, x);
#pragma unroll
                for (int j = 0; j < 8; ++j) acc[j] = fmaf(e0, x[j], acc[j]);
                unpack8(r1, x);
#pragma unroll
                for (int j = 0; j < 8; ++j) acc[j] = fmaf(e1, x[j], acc[j]);
                unpack8(r2, x);
#pragma unroll
                for (int j = 0; j < 8; ++j) acc[j] = fmaf(e2, x[j], acc[j]);
                unpack8(r3, x);
#pragma unroll
                for (int j = 0; j < 8; ++j) acc[j] = fmaf(e3, x[j], acc[j]);
            }
            idx += 16;
        }
        if (idx < end) {
            const int i1 = idx + 4, i2 = idx + 8;
            const bool v1 = i1 < end, v2 = i2 < end;
            const int d0 = sorted_dst[idx];
            const int d1 = sorted_dst[v1 ? i1 : idx];
            const int d2 = sorted_dst[v2 ? i2 : idx];
            const float4 r0 = *(const float4*)(Xb + (size_t)d0 * D + ql * 8);
            const float4 r1 = *(const float4*)(Xb + (size_t)d1 * D + ql * 8);
            const float4 r2 = *(const float4*)(Xb + (size_t)d2 * D + ql * 8);
            float t0 = 0.f, t1 = 0.f, t2 = 0.f;
            {
                float x[8];
                unpack8(r0, x);
#pragma unroll
                for (int j = 0; j < 8; ++j) t0 = fmaf(hm[j], x[j], t0);
                unpack8(r1, x);
#pragma unroll
                for (int j = 0; j < 8; ++j) t1 = fmaf(hm[j], x[j], t1);
                unpack8(r2, x);
#pragma unroll
                for (int j = 0; j < 8; ++j) t2 = fmaf(hm[j], x[j], t2);
            }
            t0 = rsum16(t0);
            t1 = rsum16(t1);
            t2 = rsum16(t2);
            float e0 = t0 > 0.f ? t0 : NEG_SLOPE * t0;
            float e1 = t1 > 0.f ? t1 : NEG_SLOPE * t1;
            float e2 = t2 > 0.f ? t2 : NEG_SLOPE * t2;
            e1 = v1 ? e1 : 0.f;
            e2 = v2 ? e2 : 0.f;
            {
                float x[8];
                unpack8(r0, x);
#pragma unroll
                for (int j = 0; j < 8; ++j) acc[j] = fmaf(e0, x[j], acc[j]);
                unpack8(r1, x);
#pragma unroll
                for (int j = 0; j < 8; ++j) acc[j] = fmaf(e1, x[j], acc[j]);
                unpack8(r2, x);
#pragma unroll
                for (int j = 0; j < 8; ++j) acc[j] = fmaf(e2, x[j], acc[j]);
            }
        }
    }

#pragma unroll
    for (int j = 0; j < 8; ++j) {
        acc[j] += __shfl_xor(acc[j], 16);
        acc[j] += __shfl_xor(acc[j], 32);
    }
    if (q == 0) {
        ushort4 o0, o1;
        o0.x = f2bf(acc[0]); o0.y = f2bf(acc[1]); o0.z = f2bf(acc[2]); o0.w = f2bf(acc[3]);
        o1.x = f2bf(acc[4]); o1.y = f2bf(acc[5]); o1.z = f2bf(acc[6]); o1.w = f2bf(acc[7]);
        *(ushort4*)&As[wave * APAD + ql * 8] = o0;
        *(ushort4*)&As[wave * APAD + ql * 8 + 4] = o1;
    }
    __syncthreads();

    // ---- fused @W: waves 0..3 each compute 16 rows x 32 cols via 8 MFMAs ----
    if (wave < 4) {
        const int m = lane & 15, kq = lane >> 4;
        f32x4 oacc[2] = {};
        const unsigned short* Arow = &As[m * APAD + kq * 8];
#pragma unroll
        for (int kc = 0; kc < 4; ++kc) {
            const bf16x8 af = *(const bf16x8*)(Arow + kc * 32);
#pragma unroll
            for (int tt = 0; tt < 2; ++tt) {
                const int t2 = wave * 2 + tt;
                const bf16x8 bf = *(const bf16x8*)&Ws[(t2 * 16 + m) * APAD + kc * 32 + kq * 8];
                oacc[tt] = __builtin_amdgcn_mfma_f32_16x16x32_bf16(af, bf, oacc[tt], 0, 0, 0);
            }
        }
        const int rbase = blockIdx.x * SPMM_NODES + kq * 4;  // C/D: col=lane&15, row=kq*4+r
#pragma unroll
        for (int tt = 0; tt < 2; ++tt) {
            const int t2 = wave * 2 + tt;
#pragma unroll
            for (int r = 0; r < 4; ++r) {
                agg[(size_t)(rbase + r) * D + t2 * 16 + m] = oacc[tt][r];
            }
        }
    }
}

extern "C" void kernel_launch(void* const* d_in, const int* in_sizes, int n_in,
                              void* d_out, int out_size, void* d_ws, size_t ws_size,
                              hipStream_t stream) {
    const float* X   = (const float*)d_in[0];
    const float* W   = (const float*)d_in[1];
    const float* W_r = (const float*)d_in[2];
    const float* W_l = (const float*)d_in[3];
    const int* src   = (const int*)d_in[4];
    const int* dst   = (const int*)d_in[5];
    float* agg = (float*)d_out;

    // workspace (~36 MB)
    ushort* Xb          = (ushort*)d_ws;                  // 6.4M ushort
    ushort* hMb         = Xb + (size_t)N_NODES * D;       // 6.4M
    ushort* MbT         = hMb + (size_t)N_NODES * D;      // 16384
    ushort* WbT         = MbT + D * D;                    // 16384
    int*    offsets     = (int*)(WbT + D * D);            // 50000
    int*    sorted_dst  = offsets + N_NODES;              // 800000
    int*    bucket_fill = sorted_dst + N_EDGES;           // 256
    int*    binned      = bucket_fill + 256;              // FB*BCAP int (packed)

    prep_kernel<<<64, 256, 0, stream>>>(W_l, W_r, W, MbT, WbT, bucket_fill);

    k1_kernel<<<BIN_NBLK + GGRID, 256, 0, stream>>>(
        src, dst, bucket_fill, binned, MbT, (const float4*)X, Xb, hMb);

    fine_kernel<<<FB, 512, 0, stream>>>(binned, bucket_fill, offsets, sorted_dst);

    spmm_fused_kernel<<<SPMM_GRID, 1024, 0, stream>>>(
        hMb, Xb, offsets, sorted_dst, WbT, agg);
}

// Round 13
// 154.302 us; speedup vs baseline: 1.6025x; 1.6025x over previous
//
#include <hip/hip_runtime.h>
#include <hip/hip_bf16.h>

#define N_NODES 50000
#define N_EDGES 800000
#define D 128
#define NEG_SLOPE 0.2f
#define APAD 136                             // LDS row pitch (ushort): 2-way-only bank aliasing

#define FB 196                               // fine buckets: src >> 8 (256 nodes each)
#define BCAP 8192                            // per-bucket region capacity (avg fill ~4096)
#define CHUNK 2048
#define BIN_NBLK ((N_EDGES + CHUNK - 1) / CHUNK)   // 391
#define GROWS 64
#define GGRID ((N_NODES + GROWS - 1) / GROWS)      // 782
#define GEMM_LDS (D * APAD * 2 + GROWS * APAD * 2) // 52224 B

#define SPMM_NODES 16                               // nodes (waves) per fused spmm block
#define SPMM_GRID (N_NODES / SPMM_NODES)            // 3125 exact
#define SPMM_LDS ((D * APAD + SPMM_NODES * APAD) * 2) // 39168 B (W staged in LDS: R12 showed
                                                      // gather streaming evicts W from L2)

typedef __attribute__((ext_vector_type(8))) short bf16x8;
typedef __attribute__((ext_vector_type(4))) float f32x4;

__device__ inline unsigned short f2bf(float f) {
    union { float f; unsigned u; } v; v.f = f;
    const unsigned r = v.u + 0x7FFF + ((v.u >> 16) & 1);   // round-nearest-even
    return (unsigned short)(r >> 16);
}
__device__ inline unsigned fbits(float f) { union { float f; unsigned u; } v; v.f = f; return v.u; }
__device__ inline float ffrom(unsigned u) { union { unsigned u; float f; } v; v.u = u; return v.f; }

__device__ inline void unpack8(const float4 raw, float* o) {
    const unsigned w0 = fbits(raw.x), w1 = fbits(raw.y), w2 = fbits(raw.z), w3 = fbits(raw.w);
    o[0] = ffrom(w0 << 16); o[1] = ffrom(w0 & 0xffff0000u);
    o[2] = ffrom(w1 << 16); o[3] = ffrom(w1 & 0xffff0000u);
    o[4] = ffrom(w2 << 16); o[5] = ffrom(w2 & 0xffff0000u);
    o[6] = ffrom(w3 << 16); o[7] = ffrom(w3 & 0xffff0000u);
}

// 16-lane (quarter-wave) sum via DPP rotate-adds: pure VALU, no LDS pipe.
// Safe under inter-quarter divergence: each 16-lane row is branch-uniform and
// DPP row ops never read across rows.
__device__ __forceinline__ float rsum16(float t) {
    union { float f; int i; } u, s;
    u.f = t;
    s.i = __builtin_amdgcn_update_dpp(0, u.i, 0x128, 0xF, 0xF, true); u.f += s.f; // ror 8
    s.i = __builtin_amdgcn_update_dpp(0, u.i, 0x124, 0xF, 0xF, true); u.f += s.f; // ror 4
    s.i = __builtin_amdgcn_update_dpp(0, u.i, 0x4E,  0xF, 0xF, true); u.f += s.f; // quad rot 2
    s.i = __builtin_amdgcn_update_dpp(0, u.i, 0x39,  0xF, 0xF, true); u.f += s.f; // quad rot 1
    return u.f;
}

// inclusive scan of 256 values (4 waves) — shfl_up intra-wave, one barrier.
__device__ __forceinline__ int scan256_incl_fast(int* wsum, int t, int v) {
    const int lane = t & 63;
    int x = v;
#pragma unroll
    for (int off = 1; off < 64; off <<= 1) {
        const int u = __shfl_up(x, off, 64);
        if (lane >= off) x += u;
    }
    if (lane == 63) wsum[t >> 6] = x;
    __syncthreads();
    int base = 0;
#pragma unroll
    for (int wv = 0; wv < 3; ++wv)
        base += (wv < (t >> 6)) ? wsum[wv] : 0;
    return x + base;
}

// inclusive scan across a 512-thread block (8 waves); threads t>=256 pass v=0.
__device__ __forceinline__ int scan_incl_512(int* wsum, int t, int v) {
    const int lane = t & 63;
    int x = v;
#pragma unroll
    for (int off = 1; off < 64; off <<= 1) {
        const int u = __shfl_up(x, off, 64);
        if (lane >= off) x += u;
    }
    if (lane == 63) wsum[t >> 6] = x;
    __syncthreads();
    int base = 0;
#pragma unroll
    for (int wv = 0; wv < 7; ++wv)
        base += (wv < (t >> 6)) ? wsum[wv] : 0;
    return x + base;
}

// stage a 128x128 bf16 matrix (transposed layout [n][k]) into LDS [n][APAD]
__device__ __forceinline__ void stage_B_lds(unsigned short* Bs, const ushort* __restrict__ BT) {
    const int tid = threadIdx.x;
#pragma unroll
    for (int i = 0; i < 8; ++i) {
        const int idx = tid + i * 256;
        const int row = idx >> 4;
        const int c8 = (idx & 15) << 3;
        const float4 v = ((const float4*)BT)[idx];
        *(float4*)&Bs[row * APAD + c8] = v;
    }
}

// MFMA: C[rb..rb+63][0..127] = As(LDS) @ Bs(LDS, transposed), fp32 acc
template <bool OUT_F32>
__device__ __forceinline__ void mfma_from_lds(const unsigned short* Bs,
                                              const unsigned short* As,
                                              int rb, float* __restrict__ Cf,
                                              ushort* __restrict__ Cb, int nrows) {
    const int tid = threadIdx.x;
    const int w = tid >> 6, lane = tid & 63, m = lane & 15, kq = lane >> 4;
    f32x4 acc[8] = {};
    const unsigned short* Arow = &As[(w * 16 + m) * APAD + kq * 8];
#pragma unroll
    for (int kc = 0; kc < 4; ++kc) {
        const bf16x8 af = *(const bf16x8*)(Arow + kc * 32);
#pragma unroll
        for (int t2 = 0; t2 < 8; ++t2) {
            const bf16x8 bf = *(const bf16x8*)&Bs[(t2 * 16 + m) * APAD + kc * 32 + kq * 8];
            acc[t2] = __builtin_amdgcn_mfma_f32_16x16x32_bf16(af, bf, acc[t2], 0, 0, 0);
        }
    }
    const int orow0 = rb + w * 16 + kq * 4;   // C/D: col=lane&15, row=(lane>>4)*4+reg [m89]
#pragma unroll
    for (int t2 = 0; t2 < 8; ++t2) {
#pragma unroll
        for (int r = 0; r < 4; ++r) {
            const int row = orow0 + r;
            if (row < nrows) {
                const size_t o = (size_t)row * D + t2 * 16 + m;
                if (OUT_F32) Cf[o] = acc[t2][r];
                else         Cb[o] = f2bf(acc[t2][r]);
            }
        }
    }
}

// ---- K0 (tiny): weight prep + zero bucket_fill. MUST be its own dispatch:
// consumers (K1 gemm1 branch / spmm_fused) are separate launches -> stream-ordered.
__global__ __launch_bounds__(256) void prep_kernel(const float* __restrict__ W_l,
                                                   const float* __restrict__ W_r,
                                                   const float* __restrict__ W,
                                                   ushort* __restrict__ MbT,
                                                   ushort* __restrict__ WbT,
                                                   int* __restrict__ bucket_fill) {
    if (blockIdx.x == 0) bucket_fill[threadIdx.x] = 0;   // 256 entries
    // MbT[n][k] = (W_l @ W_r^T)[k][n]; WbT[n][k] = W[k][n]
    const int a = blockIdx.x * 2 + (threadIdx.x >> 7);   // k
    const int b2 = threadIdx.x & 127;                    // n
    float acc = 0.f;
#pragma unroll
    for (int c = 0; c < D; c += 4) {
        const float4 wl = *(const float4*)(W_l + a * D + c);
        const float4 wr = *(const float4*)(W_r + b2 * D + c);
        acc += wl.x * wr.x + wl.y * wr.y + wl.z * wr.z + wl.w * wr.w;
    }
    MbT[b2 * D + a] = f2bf(acc);
    WbT[b2 * D + a] = f2bf(W[a * D + b2]);
}

// ---- K1: bin (blocks 0..390) + convert_gemm1 (391..) — binned entries
// packed to ONE int ((src<<16)|dst; both < 2^16). LDS-staged binning kept
// (R14 lesson: per-edge global atomics ~60-75ns each -> 50-60us kernels).
__global__ __launch_bounds__(256) void k1_kernel(const int* __restrict__ src,
                                                 const int* __restrict__ dst,
                                                 int* __restrict__ bucket_fill,
                                                 int* __restrict__ binned,
                                                 const ushort* __restrict__ MbT,
                                                 const float4* __restrict__ Xf4,
                                                 ushort* __restrict__ Xb,
                                                 ushort* __restrict__ hMb) {
    __shared__ __align__(16) char smem[GEMM_LDS];
    const int bx = blockIdx.x;
    const int t = threadIdx.x;

    if (bx < BIN_NBLK) {
        int*  hist     = (int*)smem;                 // 256
        int*  bstart   = hist + 256;                 // 256 (first 4 double as wave-sum scratch)
        int*  reserveS = bstart + 256;               // 256
        int*  fillL    = reserveS + 256;             // 256
        int*  pairs    = fillL + 256;                // CHUNK (8 KB, packed)
        int*  targ     = pairs + CHUNK;              // CHUNK (8 KB)
        const int e0 = bx * CHUNK;

        hist[t] = 0;
        __syncthreads();

        int s[8], d[8], b[8];
#pragma unroll
        for (int i = 0; i < 8; ++i) {
            const int e = e0 + i * 256 + t;
            if (e < N_EDGES) {
                s[i] = src[e]; d[i] = dst[e]; b[i] = s[i] >> 8;
                atomicAdd(&hist[b[i]], 1);
            } else b[i] = -1;
        }
        __syncthreads();
        const int hv = hist[t];
        const int incl = scan256_incl_fast(bstart, t, hv);   // 1 barrier
        const int mystart = incl - hv;
        reserveS[t] = hv ? atomicAdd(&bucket_fill[t], hv) : 0;
        __syncthreads();                 // also fences wave-sum reads before overwrite
        bstart[t] = mystart;
        fillL[t] = mystart;
        __syncthreads();
#pragma unroll
        for (int i = 0; i < 8; ++i) {
            if (b[i] >= 0) {
                const int p = atomicAdd(&fillL[b[i]], 1);
                pairs[p] = (s[i] << 16) | d[i];
                const int pos = reserveS[b[i]] + (p - bstart[b[i]]);
                targ[p] = (pos < BCAP) ? (b[i] * BCAP + pos) : -1;   // overflow guard
            }
        }
        __syncthreads();
        const int nval = min(CHUNK, N_EDGES - e0);
        for (int j = t; j < nval; j += 256)
            if (targ[j] >= 0) binned[targ[j]] = pairs[j];
    } else {
        // ---- convert 64 X-rows fp32->bf16 (global + LDS) then hM = Xb@M ----
        unsigned short* Bs = (unsigned short*)smem;     // [128][APAD]
        unsigned short* As = Bs + D * APAD;             // [64][APAD]
        const int rb = (bx - BIN_NBLK) * GROWS;

        stage_B_lds(Bs, MbT);                           // MbT from K0 (stream-ordered)
#pragma unroll
        for (int i = 0; i < 4; ++i) {
            const int f2 = t + i * 256;
            const int row = f2 >> 4;
            const int c8 = (f2 & 15) << 3;
            ushort4 lo = {0, 0, 0, 0}, hi = {0, 0, 0, 0};
            if (rb + row < N_NODES) {
                const float4 a = Xf4[(size_t)(rb + row) * 32 + (c8 >> 2)];
                const float4 b = Xf4[(size_t)(rb + row) * 32 + (c8 >> 2) + 1];
                lo.x = f2bf(a.x); lo.y = f2bf(a.y); lo.z = f2bf(a.z); lo.w = f2bf(a.w);
                hi.x = f2bf(b.x); hi.y = f2bf(b.y); hi.z = f2bf(b.z); hi.w = f2bf(b.w);
                ushort* gp = Xb + (size_t)(rb + row) * D + c8;
                *(ushort4*)gp = lo;
                *(ushort4*)(gp + 4) = hi;
            }
            *(ushort4*)&As[row * APAD + c8] = lo;
            *(ushort4*)&As[row * APAD + c8 + 4] = hi;
        }
        __syncthreads();
        mfma_from_lds<false>(Bs, As, rb, nullptr, hMb, N_NODES);
    }
}

// ---- K2: fine scatter, one 512-thread block per bucket; builds offsets+sorted_dst ----
__global__ __launch_bounds__(512) void fine_kernel(const int* __restrict__ binned,
                                                   const int* __restrict__ bucket_fill,
                                                   int* __restrict__ offsets,
                                                   int* __restrict__ sorted_dst) {
    __shared__ int cntS[256];
    __shared__ int nh[256];
    __shared__ int fill[256];
    __shared__ int wsum[8];
    __shared__ int dstbuf[BCAP];
    const int b = blockIdx.x;
    const int t = threadIdx.x;

    int cv = 0;
    if (t < 256) cv = (t < FB) ? bucket_fill[t] : 0;
    const int incl = scan_incl_512(wsum, t, cv);        // 1 barrier
    if (t < 256) cntS[t] = incl;
    __syncthreads();
    const int base = (b == 0) ? 0 : cntS[b - 1];
    int cnt = cntS[b] - base;
    if (cnt > BCAP) cnt = BCAP;

    if (t < 256) nh[t] = 0;
    __syncthreads();
    const int* bb = binned + (size_t)b * BCAP;
    for (int e = t; e < cnt; e += 512) atomicAdd(&nh[((unsigned)bb[e] >> 16) & 255], 1);
    __syncthreads();
    const int v = (t < 256) ? nh[t] : 0;
    const int incl2 = scan_incl_512(wsum, t, v);        // 1 barrier
    if (t < 256) {
        const int mystart = incl2 - v;
        const int node = b * 256 + t;
        if (node < N_NODES) offsets[node] = base + mystart;   // exclusive CSR starts
        fill[t] = mystart;
    }
    __syncthreads();
    for (int e = t; e < cnt; e += 512) {
        const int sd = bb[e];
        const int p = atomicAdd(&fill[((unsigned)sd >> 16) & 255], 1);
        dstbuf[p] = sd & 0xFFFF;
    }
    __syncthreads();
    for (int j = t; j < cnt; j += 512)
        sorted_dst[base + j] = dstbuf[j];
}

// ---- K3 (R11, FINAL): fused SDDMM + SpMM + @W. 16 waves = 16 nodes/block.
// The edge-loop shape is a verified local optimum; five restructurings lost:
//  R3  (batched single-unpack)  -> 200MB spill (x[] arrays live across rsum16)
//  R6  (2 waves/node)           -> +30% instr (per-wave fixed-overhead tax)
//  R7  (flat 5-slot round)      -> 450MB spill (5th float4 exceeds 32-VGPR)
//  R19 ((1024,4) + seq unpack)  -> occupancy 62->38%, row chains serialized
//  R20 (LDS dst-list + fallback)-> 355MB spill (duplicated loop body state)
// Dual unpack per row is what buys 4-row ILP at 32 VGPR / 8 waves/EU.
// W staged in LDS (R12: gather streaming evicts W from L2). DO NOT MODIFY.
__global__ __launch_bounds__(1024, 8) void spmm_fused_kernel(const ushort* __restrict__ hMb,
                                                             const ushort* __restrict__ Xb,
                                                             const int* __restrict__ offsets,
                                                             const int* __restrict__ sorted_dst,
                                                             const ushort* __restrict__ WbT,
                                                             float* __restrict__ agg) {
    __shared__ __align__(16) char smem[SPMM_LDS];
    unsigned short* Ws = (unsigned short*)smem;          // [128][APAD] : W (transposed [n][k])
    unsigned short* As = Ws + D * APAD;                  // [16][APAD]  : node rows (bf16)
    const int tid = threadIdx.x;

    // stage W: 2048 float4 over 1024 threads
#pragma unroll
    for (int i = 0; i < 2; ++i) {
        const int idx = tid + i * 1024;
        const int row = idx >> 4;
        const int c8 = (idx & 15) << 3;
        const float4 v = ((const float4*)WbT)[idx];
        *(float4*)&Ws[row * APAD + c8] = v;
    }

    const int wave = tid >> 6;
    const int lane = tid & 63;
    const int node = blockIdx.x * SPMM_NODES + wave;     // 3125*16 = 50000 exact
    const int q = lane >> 4;
    const int ql = lane & 15;

    float hm[8];
    unpack8(*(const float4*)(hMb + (size_t)node * D + ql * 8), hm);

    const int start = offsets[node];
    const int end = (node == N_NODES - 1) ? N_EDGES : offsets[node + 1];

    float acc[8] = {0.f, 0.f, 0.f, 0.f, 0.f, 0.f, 0.f, 0.f};

    int idx = start + q;
    while (idx + 12 < end) {
        const int d0 = sorted_dst[idx];
        const int d1 = sorted_dst[idx + 4];
        const int d2 = sorted_dst[idx + 8];
        const int d3 = sorted_dst[idx + 12];
        const float4 r0 = *(const float4*)(Xb + (size_t)d0 * D + ql * 8);
        const float4 r1 = *(const float4*)(Xb + (size_t)d1 * D + ql * 8);
        const float4 r2 = *(const float4*)(Xb + (size_t)d2 * D + ql * 8);
        const float4 r3 = *(const float4*)(Xb + (size_t)d3 * D + ql * 8);
        float t0 = 0.f, t1 = 0.f, t2 = 0.f, t3 = 0.f;
        {
            float x[8];
            unpack8(r0, x);
#pragma unroll
            for (int j = 0; j < 8; ++j) t0 = fmaf(hm[j], x[j], t0);
            unpack8(r1, x);
#pragma unroll
            for (int j = 0; j < 8; ++j) t1 = fmaf(hm[j], x[j], t1);
            unpack8(r2, x);
#pragma unroll
            for (int j = 0; j < 8; ++j) t2 = fmaf(hm[j], x[j], t2);
            unpack8(r3, x);
#pragma unroll
            for (int j = 0; j < 8; ++j) t3 = fmaf(hm[j], x[j], t3);
        }
        t0 = rsum16(t0);
        t1 = rsum16(t1);
        t2 = rsum16(t2);
        t3 = rsum16(t3);
        const float e0 = t0 > 0.f ? t0 : NEG_SLOPE * t0;
        const float e1 = t1 > 0.f ? t1 : NEG_SLOPE * t1;
        const float e2 = t2 > 0.f ? t2 : NEG_SLOPE * t2;
        const float e3 = t3 > 0.f ? t3 : NEG_SLOPE * t3;
        {
            float x[8];
            unpack8(r0, x);
#pragma unroll
            for (int j = 0; j < 8; ++j) acc[j] = fmaf(e0, x[j], acc[j]);
            unpack8(r1, x);
#pragma unroll
            for (int j = 0; j < 8; ++j) acc[j] = fmaf(e1, x[j], acc[j]);
            unpack8(r2, x);
#pragma unroll
            for (int j = 0; j < 8; ++j) acc[j] = fmaf(e2, x[j], acc[j]);
            unpack8(r3, x);
#pragma unroll
            for (int j = 0; j < 8; ++j) acc[j] = fmaf(e3, x[j], acc[j]);
        }
        idx += 16;
    }
    // masked-parallel tail: at most edges {idx, idx+4, idx+8} remain per quarter.
    if (idx < end) {
        const int i1 = idx + 4, i2 = idx + 8;
        const bool v1 = i1 < end, v2 = i2 < end;
        const int d0 = sorted_dst[idx];
        const int d1 = sorted_dst[v1 ? i1 : idx];
        const int d2 = sorted_dst[v2 ? i2 : idx];
        const float4 r0 = *(const float4*)(Xb + (size_t)d0 * D + ql * 8);
        const float4 r1 = *(const float4*)(Xb + (size_t)d1 * D + ql * 8);
        const float4 r2 = *(const float4*)(Xb + (size_t)d2 * D + ql * 8);
        float t0 = 0.f, t1 = 0.f, t2 = 0.f;
        {
            float x[8];
            unpack8(r0, x);
#pragma unroll
            for (int j = 0; j < 8; ++j) t0 = fmaf(hm[j], x[j], t0);
            unpack8(r1, x);
#pragma unroll
            for (int j = 0; j < 8; ++j) t1 = fmaf(hm[j], x[j], t1);
            unpack8(r2, x);
#pragma unroll
            for (int j = 0; j < 8; ++j) t2 = fmaf(hm[j], x[j], t2);
        }
        t0 = rsum16(t0);
        t1 = rsum16(t1);
        t2 = rsum16(t2);
        float e0 = t0 > 0.f ? t0 : NEG_SLOPE * t0;
        float e1 = t1 > 0.f ? t1 : NEG_SLOPE * t1;
        float e2 = t2 > 0.f ? t2 : NEG_SLOPE * t2;
        e1 = v1 ? e1 : 0.f;
        e2 = v2 ? e2 : 0.f;
        {
            float x[8];
            unpack8(r0, x);
#pragma unroll
            for (int j = 0; j < 8; ++j) acc[j] = fmaf(e0, x[j], acc[j]);
            unpack8(r1, x);
#pragma unroll
            for (int j = 0; j < 8; ++j) acc[j] = fmaf(e1, x[j], acc[j]);
            unpack8(r2, x);
#pragma unroll
            for (int j = 0; j < 8; ++j) acc[j] = fmaf(e2, x[j], acc[j]);
        }
    }

#pragma unroll
    for (int j = 0; j < 8; ++j) {
        acc[j] += __shfl_xor(acc[j], 16);
        acc[j] += __shfl_xor(acc[j], 32);
    }
    if (q == 0) {
        ushort4 o0, o1;
        o0.x = f2bf(acc[0]); o0.y = f2bf(acc[1]); o0.z = f2bf(acc[2]); o0.w = f2bf(acc[3]);
        o1.x = f2bf(acc[4]); o1.y = f2bf(acc[5]); o1.z = f2bf(acc[6]); o1.w = f2bf(acc[7]);
        *(ushort4*)&As[wave * APAD + ql * 8] = o0;
        *(ushort4*)&As[wave * APAD + ql * 8 + 4] = o1;
    }
    __syncthreads();

    // ---- fused @W: waves 0..3 each compute 16 rows x 32 cols via 8 MFMAs ----
    if (wave < 4) {
        const int m = lane & 15, kq = lane >> 4;
        f32x4 oacc[2] = {};
        const unsigned short* Arow = &As[m * APAD + kq * 8];
#pragma unroll
        for (int kc = 0; kc < 4; ++kc) {
            const bf16x8 af = *(const bf16x8*)(Arow + kc * 32);
#pragma unroll
            for (int tt = 0; tt < 2; ++tt) {
                const int t2 = wave * 2 + tt;
                const bf16x8 bf = *(const bf16x8*)&Ws[(t2 * 16 + m) * APAD + kc * 32 + kq * 8];
                oacc[tt] = __builtin_amdgcn_mfma_f32_16x16x32_bf16(af, bf, oacc[tt], 0, 0, 0);
            }
        }
        const int rbase = blockIdx.x * SPMM_NODES + kq * 4;  // C/D: col=lane&15, row=kq*4+r
#pragma unroll
        for (int tt = 0; tt < 2; ++tt) {
            const int t2 = wave * 2 + tt;
#pragma unroll
            for (int r = 0; r < 4; ++r) {
                agg[(size_t)(rbase + r) * D + t2 * 16 + m] = oacc[tt][r];
            }
        }
    }
}

extern "C" void kernel_launch(void* const* d_in, const int* in_sizes, int n_in,
                              void* d_out, int out_size, void* d_ws, size_t ws_size,
                              hipStream_t stream) {
    const float* X   = (const float*)d_in[0];
    const float* W   = (const float*)d_in[1];
    const float* W_r = (const float*)d_in[2];
    const float* W_l = (const float*)d_in[3];
    const int* src   = (const int*)d_in[4];
    const int* dst   = (const int*)d_in[5];
    float* agg = (float*)d_out;

    // workspace (~36 MB)
    ushort* Xb          = (ushort*)d_ws;                  // 6.4M ushort
    ushort* hMb         = Xb + (size_t)N_NODES * D;       // 6.4M
    ushort* MbT         = hMb + (size_t)N_NODES * D;      // 16384
    ushort* WbT         = MbT + D * D;                    // 16384
    int*    offsets     = (int*)(WbT + D * D);            // 50000
    int*    sorted_dst  = offsets + N_NODES;              // 800000
    int*    bucket_fill = sorted_dst + N_EDGES;           // 256
    int*    binned      = bucket_fill + 256;              // FB*BCAP int (packed)

    prep_kernel<<<64, 256, 0, stream>>>(W_l, W_r, W, MbT, WbT, bucket_fill);

    k1_kernel<<<BIN_NBLK + GGRID, 256, 0, stream>>>(
        src, dst, bucket_fill, binned, MbT, (const float4*)X, Xb, hMb);

    fine_kernel<<<FB, 512, 0, stream>>>(binned, bucket_fill, offsets, sorted_dst);

    spmm_fused_kernel<<<SPMM_GRID, 1024, 0, stream>>>(
        hMb, Xb, offsets, sorted_dst, WbT, agg);
}